// Round 8
// baseline (272.176 us; speedup 1.0000x reference)
//
#include <hip/hip_runtime.h>
#include <hip/hip_bf16.h>

#define NN 100000
#define EE 1600000
#define INC 256
#define OUTC 128
#define NBUK 782            // ceil(100000 / 128) node buckets
#define NPB  256            // partition blocks
#define CHUNK ((EE + NPB - 1) / NPB)   // 6250 edges per partition block
#define NSL 8               // h2 column slices (one per XCD)
#define GNPB 16             // gather: nodes per block (4 per wave)

typedef short bf16x8 __attribute__((ext_vector_type(8)));
typedef float f32x4 __attribute__((ext_vector_type(4)));

static __device__ __forceinline__ unsigned short f2bf(float f){
    unsigned u = __builtin_bit_cast(unsigned, f);
    u += 0x7fffu + ((u >> 16) & 1u);
    return (unsigned short)(u >> 16);
}
static __device__ __forceinline__ float bf2f(unsigned short h){
    unsigned u = ((unsigned)h) << 16;
    return __builtin_bit_cast(float, u);
}

// ---------- bucket histogram (LDS-aggregated) ----------
__global__ void hist_kernel(const int* __restrict__ col, unsigned* __restrict__ bcnt){
    __shared__ unsigned h[NBUK];
    for (int i = threadIdx.x; i < NBUK; i += 256) h[i] = 0;
    __syncthreads();
    for (int i = blockIdx.x*blockDim.x + threadIdx.x; i < EE; i += gridDim.x*blockDim.x)
        atomicAdd(&h[((unsigned)col[i]) >> 7], 1u);
    __syncthreads();
    for (int i = threadIdx.x; i < NBUK; i += 256)
        if (h[i]) atomicAdd(&bcnt[i], h[i]);
}

// ---------- scan of 782 bucket counts -> base, cursor ----------
__global__ void scanb_kernel(const unsigned* __restrict__ bcnt,
                             unsigned* __restrict__ base, unsigned* __restrict__ cursor){
    __shared__ unsigned tmp[1024];
    int t = threadIdx.x;
    unsigned v = (t < NBUK) ? bcnt[t] : 0u;
    tmp[t] = v;
    __syncthreads();
    for (int off = 1; off < 1024; off <<= 1){
        unsigned x = (t >= off) ? tmp[t-off] : 0u;
        __syncthreads();
        tmp[t] += x;
        __syncthreads();
    }
    if (t < NBUK){ unsigned ex = tmp[t] - v; base[t] = ex; cursor[t] = ex; }
    if (t == 0) base[NBUK] = EE;
}

// ---------- partition edges into bucket regions (block-batched reservations) ----------
__global__ void partition_kernel(const int* __restrict__ ei, unsigned* __restrict__ cursor,
                                 unsigned* __restrict__ packed){
    __shared__ unsigned cnt[NBUK], gpos[NBUK], cnt2[NBUK];
    int t = threadIdx.x;
    int s = blockIdx.x*CHUNK, e = min(s + CHUNK, EE);
    for (int i = t; i < NBUK; i += 256){ cnt[i] = 0; cnt2[i] = 0; }
    __syncthreads();
    for (int i = s + t; i < e; i += 256)
        atomicAdd(&cnt[((unsigned)ei[EE + i]) >> 7], 1u);
    __syncthreads();
    for (int i = t; i < NBUK; i += 256){
        unsigned c = cnt[i];
        gpos[i] = c ? atomicAdd(&cursor[i], c) : 0u;
    }
    __syncthreads();
    for (int i = s + t; i < e; i += 256){
        unsigned c = (unsigned)ei[EE + i];
        unsigned r = (unsigned)ei[i];
        unsigned b = c >> 7;
        unsigned rk = atomicAdd(&cnt2[b], 1u);
        packed[gpos[b] + rk] = ((c & 127u) << 24) | r;
    }
}

// ---------- per-bucket counting sort -> CSR (erow, noffs) + dinv ----------
__global__ void sort_kernel(const unsigned* __restrict__ packed, const unsigned* __restrict__ base,
                            unsigned* __restrict__ erow, unsigned* __restrict__ noffs,
                            float* __restrict__ dinv){
    __shared__ unsigned cnt[128], cur[128], tmp[128];
    int t = threadIdx.x;
    unsigned s = base[blockIdx.x], e = base[blockIdx.x + 1];
    if (t < 128) cnt[t] = 0;
    __syncthreads();
    for (unsigned i = s + t; i < e; i += 256)
        atomicAdd(&cnt[packed[i] >> 24], 1u);
    __syncthreads();
    if (t < 128) tmp[t] = cnt[t];
    __syncthreads();
    for (int off = 1; off < 128; off <<= 1){
        unsigned v = (t >= off && t < 128) ? tmp[t-off] : 0u;
        __syncthreads();
        if (t < 128) tmp[t] += v;
        __syncthreads();
    }
    if (t < 128){
        unsigned ex = s + tmp[t] - cnt[t];   // global CSR offset for this node
        cur[t] = ex;
        int node = blockIdx.x*128 + t;
        if (node < NN){
            noffs[node] = ex;
            dinv[node] = cnt[t] ? rsqrtf((float)cnt[t]) : 0.f;
        }
    }
    if (blockIdx.x == 0 && t == 0) noffs[NN] = EE;
    __syncthreads();
    for (unsigned i = s + t; i < e; i += 256){
        unsigned u = packed[i];
        unsigned pos = atomicAdd(&cur[u >> 24], 1u);
        erow[pos] = u & 0xFFFFFFu;
    }
}

// ---------- W -> fragment-ordered bf16 (one-time prep) ----------
__global__ void wprep_kernel(const float* __restrict__ w, unsigned short* __restrict__ wfrag){
    int idx = blockIdx.x*256 + threadIdx.x;
    if (idx < 8*8*64*8){
        int r = idx & 7, l = (idx >> 3) & 63, t = (idx >> 9) & 7, s = idx >> 12;
        int n = t*16 + (l & 15);
        int k = s*32 + ((l >> 4) << 3) + r;
        wfrag[idx] = f2bf(w[n*INC + k]);
    }
}

// ---------- GEMM (round-6 body): h2s[slice][row][16] = dinv*perm/sign(x@W^T) ----------
__launch_bounds__(256, 4)
__global__ void gemm_kernel(const float* __restrict__ x, const unsigned short* __restrict__ wfrag,
                            const float* __restrict__ dinv,
                            unsigned short* __restrict__ h2s, int Nn){
    int tid = threadIdx.x;
    int wave = tid >> 6, lane = tid & 63;
    int mrow = blockIdx.x*64 + wave*16 + (lane & 15);
    const float* xr = x + (size_t)min(mrow, Nn-1) * INC;
    int kg = (lane >> 4) << 3;   // 0,8,16,24
    const bf16x8* wf = (const bf16x8*)wfrag;   // [(s*8+t)*64 + lane]

    f32x4 acc[8];
    #pragma unroll
    for (int t = 0; t < 8; ++t) acc[t] = (f32x4){0.f,0.f,0.f,0.f};

    #pragma unroll
    for (int s = 0; s < 8; ++s){
        const float4* p = (const float4*)(xr + s*32 + kg);
        float4 a0 = p[0], a1 = p[1];
        bf16x8 af;
        af[0]=f2bf(a0.x); af[1]=f2bf(a0.y); af[2]=f2bf(a0.z); af[3]=f2bf(a0.w);
        af[4]=f2bf(a1.x); af[5]=f2bf(a1.y); af[6]=f2bf(a1.z); af[7]=f2bf(a1.w);
        #pragma unroll
        for (int t = 0; t < 8; ++t){
            bf16x8 bf = wf[(s*8 + t)*64 + lane];
            acc[t] = __builtin_amdgcn_mfma_f32_16x16x32_bf16(af, bf, acc[t], 0, 0, 0);
        }
    }

    int rbase = blockIdx.x*64 + wave*16 + ((lane >> 4) << 2);
    float sc[4];
    #pragma unroll
    for (int r = 0; r < 4; ++r){
        int row = rbase + r;
        sc[r] = (row < Nn) ? dinv[row] : 0.f;
    }
    #pragma unroll
    for (int t = 0; t < 8; ++t){
        int o  = t*16 + (lane & 15);          // original output channel
        int dc = (o + 64) & 127;              // rolled destination column
        float sgn = (o < 64) ? 1.f : -1.f;    // negate-second-half folded through roll
        int slice = dc >> 4, cis = dc & 15;
        #pragma unroll
        for (int r = 0; r < 4; ++r){
            int row = rbase + r;
            if (row < Nn)
                h2s[((size_t)slice*NN + row)*16 + cis] = f2bf(sgn * sc[r] * acc[t][r]);
        }
    }
}

// ---------- gather: XCD-sliced columns; uniform control flow around shfl ----------
__launch_bounds__(256)
__global__ void gather_kernel(const unsigned* __restrict__ h2su,   // u32 view of h2s
                              const unsigned* __restrict__ noffs,
                              const unsigned* __restrict__ erow,
                              const float* __restrict__ dinv,
                              float* __restrict__ out){
    int slice = blockIdx.x & 7;
    int nb = blockIdx.x >> 3;
    int wave = threadIdx.x >> 6, lane = threadIdx.x & 63;
    int g8 = lane >> 3;                 // edge slot 0..7
    int cp = lane & 7;                  // col-pair 0..7
    const unsigned* hs = h2su + (size_t)slice*NN*8;

    for (int k = 0; k < 4; ++k){
        int node = nb*GNPB + wave*4 + k;
        if (node >= NN) break;          // wave-uniform
        unsigned s = noffs[node], e = noffs[node+1];
        unsigned deg = e - s;
        float accL = 0.f, accH = 0.f;
        for (unsigned b = 0; b < deg; b += 64){
            unsigned my = b + lane;
            unsigned eidx = (my < deg) ? erow[s + my] : 0u;
            unsigned chunk = min(64u, deg - b);     // wave-uniform, >= 1
            unsigned j = 0;
            // main: 16 edges per iter (2 per slot), uniform bounds
            for (; j + 16 <= chunk; j += 16){
                unsigned r0 = __shfl(eidx, (int)(j + g8));
                unsigned r1 = __shfl(eidx, (int)(j + 8 + g8));
                unsigned v0 = hs[(size_t)r0*8 + cp];
                unsigned v1 = hs[(size_t)r1*8 + cp];
                accL += bf2f((unsigned short)(v0 & 0xFFFFu));
                accH += bf2f((unsigned short)(v0 >> 16));
                accL += bf2f((unsigned short)(v1 & 0xFFFFu));
                accH += bf2f((unsigned short)(v1 >> 16));
            }
            // 8-wide step, uniform branch
            if (j + 8 <= chunk){
                unsigned r0 = __shfl(eidx, (int)(j + g8));
                unsigned v0 = hs[(size_t)r0*8 + cp];
                accL += bf2f((unsigned short)(v0 & 0xFFFFu));
                accH += bf2f((unsigned short)(v0 >> 16));
                j += 8;
            }
            // partial tail: shfl executed by ALL lanes (clamped index), accumulate predicated
            unsigned jj = j + (unsigned)g8;
            unsigned rr = __shfl(eidx, (int)(jj < chunk ? jj : chunk - 1));
            if (jj < chunk){
                unsigned v = hs[(size_t)rr*8 + cp];
                accL += bf2f((unsigned short)(v & 0xFFFFu));
                accH += bf2f((unsigned short)(v >> 16));
            }
        }
        accL += __shfl_down(accL, 32); accH += __shfl_down(accH, 32);
        accL += __shfl_down(accL, 16); accH += __shfl_down(accH, 16);
        accL += __shfl_down(accL, 8);  accH += __shfl_down(accH, 8);
        if (lane < 8){
            float wc = dinv[node];
            float2 o = {accL*wc, accH*wc};
            *(float2*)(out + (size_t)node*OUTC + slice*16 + cp*2) = o;
        }
    }
}

extern "C" void kernel_launch(void* const* d_in, const int* in_sizes, int n_in,
                              void* d_out, int out_size, void* d_ws, size_t ws_size,
                              hipStream_t stream){
    const float* x  = (const float*)d_in[0];
    const int*   ei = (const int*)d_in[1];      // [2][E]: row then col
    const float* w  = (const float*)d_in[2];    // [128][256]
    float* out = (float*)d_out;

    char* ws = (char*)d_ws;
    size_t off = 0;
    auto alloc = [&](size_t b) -> char* {
        char* p = ws + off;
        off += (b + 255) & ~(size_t)255;
        return p;
    };
    unsigned* bcnt   = (unsigned*)alloc((size_t)NBUK*4);
    unsigned* base   = (unsigned*)alloc((size_t)(NBUK+1)*4);
    unsigned* cursor = (unsigned*)alloc((size_t)NBUK*4);
    float*    dinv   = (float*)  alloc((size_t)NN*4);
    unsigned* packed = (unsigned*)alloc((size_t)EE*4);
    unsigned* erow   = (unsigned*)alloc((size_t)EE*4);
    unsigned* noffs  = (unsigned*)alloc((size_t)(NN+1)*4);
    unsigned short* wfrag = (unsigned short*)alloc((size_t)8*8*64*8*2);
    unsigned short* h2s = (unsigned short*)alloc((size_t)NN*OUTC*2);

    hipMemsetAsync(bcnt, 0, (size_t)NBUK*4, stream);
    wprep_kernel<<<128, 256, 0, stream>>>(w, wfrag);
    hist_kernel<<<256, 256, 0, stream>>>(ei + EE, bcnt);
    scanb_kernel<<<1, 1024, 0, stream>>>(bcnt, base, cursor);
    partition_kernel<<<NPB, 256, 0, stream>>>(ei, cursor, packed);
    sort_kernel<<<NBUK, 256, 0, stream>>>(packed, base, erow, noffs, dinv);
    gemm_kernel<<<(NN+63)/64, 256, 0, stream>>>(x, wfrag, dinv, h2s, NN);
    gather_kernel<<<((NN+GNPB-1)/GNPB)*NSL, 256, 0, stream>>>((const unsigned*)h2s, noffs, erow, dinv, out);
}